// Round 6
// baseline (92.354 us; speedup 1.0000x reference)
//
#include <hip/hip_runtime.h>

// x[8,256,64,64] f32, kernel[8,1,9,64,64] f32, K=3, dilation=1.
// out[n,c,h,w] = sum_{r,s} x[n,c,h+r-1,w+s-1] * ker[n,0,r*3+s,h,w]
constexpr int Cc = 256, Hh = 64, Ww = 64;
constexpr int HSEG = 4;   // rows per block; x rows loaded 1.5x (L3-absorbed)

struct Row { float4 v; float lm, rp; };

__device__ __forceinline__ Row load_row(const float* __restrict__ rowptr, bool valid,
                                        int w0, int wstrip, int lane) {
    Row r;
    if (valid) r.v = *reinterpret_cast<const float4*>(rowptr + w0);
    else       r.v = make_float4(0.f, 0.f, 0.f, 0.f);
    const float l  = __shfl(r.v.w, (lane + 63) & 63);
    const float rr = __shfl(r.v.x, (lane + 1) & 63);
    r.lm = (wstrip == 0)  ? 0.f : l;   // w-strip is the fast lane index
    r.rp = (wstrip == 15) ? 0.f : rr;
    return r;
}

__device__ __forceinline__ void conv_row(float4& acc, const Row& r,
                                         const float4& k0, const float4& k1, const float4& k2) {
    acc.x += k0.x * r.lm  + k1.x * r.v.x + k2.x * r.v.y;
    acc.y += k0.y * r.v.x + k1.y * r.v.y + k2.y * r.v.z;
    acc.z += k0.z * r.v.y + k1.z * r.v.z + k2.z * r.v.w;
    acc.w += k0.w * r.v.z + k1.w * r.v.w + k2.w * r.rp;
}

__global__ __launch_bounds__(256) void ddf_kernel(const float* __restrict__ x,
                                                  const float* __restrict__ ker,
                                                  float* __restrict__ out) {
    const int b  = blockIdx.x;
    const int hs = b & 15;          // 16 h-segments
    const int cb = (b >> 4) & 15;   // 16 channel chunks of 16
    const int n  = b >> 8;          // batch
    const int h0 = hs * HSEG;

    const int t      = threadIdx.x;
    const int lane   = t & 63;
    const int wstrip = t & 15;
    const int w0     = wstrip << 2;
    const int chl    = t >> 4;      // 0..15

    // Stage this (n, h-segment)'s kernel taps into LDS: 9 taps x 4 rows x 64 w = 9 KB.
    __shared__ float4 klds[9 * 64];   // klds[tap*64 + dh*16 + wq]
    const float4* kerf4 = reinterpret_cast<const float4*>(ker) + (size_t)n * 9 * 1024;
    for (int j = t; j < 9 * 64; j += 256) {
        const int tap = j >> 6, q = j & 63;
        klds[j] = kerf4[(size_t)tap * 1024 + h0 * 16 + q];
    }

    const int c = cb * 16 + chl;
    const float* xc = x   + ((size_t)(n * Cc + c) * Hh) * Ww;
    float*       oc = out + ((size_t)(n * Cc + c) * Hh) * Ww;

    // Prime rolling window (rows h0-1, h0) while the LDS stage is in flight.
    Row r0 = load_row(xc + (size_t)(h0 - 1) * Ww, h0 > 0, w0, wstrip, lane);
    Row r1 = load_row(xc + (size_t)h0 * Ww,       true,   w0, wstrip, lane);
    __syncthreads();

#pragma unroll
    for (int dh = 0; dh < HSEG; ++dh) {
        const int h = h0 + dh;

        float4 kf[9];
#pragma unroll
        for (int tap = 0; tap < 9; ++tap)
            kf[tap] = klds[tap * 64 + dh * 16 + wstrip];   // 2-way bank alias: free

        const bool vnext = (h + 1) < Hh;   // block-uniform
        Row r2 = load_row(xc + (size_t)(h + 1) * Ww, vnext, w0, wstrip, lane);

        float4 acc = make_float4(0.f, 0.f, 0.f, 0.f);
        conv_row(acc, r0, kf[0], kf[1], kf[2]);
        conv_row(acc, r1, kf[3], kf[4], kf[5]);
        conv_row(acc, r2, kf[6], kf[7], kf[8]);
        // Plain coherent store: nt write-around raced the harness's L2-resident
        // poison lines (post-timing divergence in R5) — do not reintroduce.
        *reinterpret_cast<float4*>(oc + (size_t)h * Ww + w0) = acc;
        r0 = r1;
        r1 = r2;
    }
}

extern "C" void kernel_launch(void* const* d_in, const int* in_sizes, int n_in,
                              void* d_out, int out_size, void* d_ws, size_t ws_size,
                              hipStream_t stream) {
    const float* x   = (const float*)d_in[0];
    const float* ker = (const float*)d_in[1];
    float* out = (float*)d_out;

    const int grid = 8 * 16 * 16;  // n * cb * hs = 2048 blocks -> 8 blocks/CU
    ddf_kernel<<<grid, 256, 0, stream>>>(x, ker, out);
}

// Round 7
// 92.048 us; speedup vs baseline: 1.0033x; 1.0033x over previous
//
#include <hip/hip_runtime.h>

// x[8,256,64,64] f32, kernel[8,1,9,64,64] f32, K=3, dilation=1.
// out[n,c,h,w] = sum_{r,s} x[n,c,h+r-1,w+s-1] * ker[n,0,r*3+s,h,w]
//
// Best-measured config (R3): NCH=2 channels/thread, 32 channels/block,
// 4-row h-segments -> 1024 blocks = 4 blocks/CU, 16 waves/CU.
// - kernel taps staged once per block into LDS (9 KB), read back with
//   2-way bank aliasing (free per m136).
// - x rows loaded once per thread via rolling 3-row register window;
//   w-halos via __shfl from lane+-1 (w-strip is the fast lane index).
// - NCH=1/2048-block variant measured SLOWER (92.4 vs 90.3): kf reads and
//   address math amortize over 2 channels, beating the extra TLP.
// - nt stores are ~2 us faster but race the harness's L2-resident poison
//   lines (post-timing divergence) — do not reintroduce.
constexpr int Cc = 256, Hh = 64, Ww = 64;
constexpr int NCH   = 2;   // channels per thread
constexpr int CHUNK = 32;  // channels per block
constexpr int HSEG  = 4;   // rows per block -> x rows loaded 1.5x (L2/L3-absorbed)

struct Row { float4 v; float lm, rp; };

__device__ __forceinline__ Row load_row(const float* __restrict__ rowptr, bool valid,
                                        int w0, int wstrip, int lane) {
    Row r;
    if (valid) r.v = *reinterpret_cast<const float4*>(rowptr + w0);
    else       r.v = make_float4(0.f, 0.f, 0.f, 0.f);
    const float l  = __shfl(r.v.w, (lane + 63) & 63);
    const float rr = __shfl(r.v.x, (lane + 1) & 63);
    r.lm = (wstrip == 0)  ? 0.f : l;   // strips 0/15 are the zero padding
    r.rp = (wstrip == 15) ? 0.f : rr;
    return r;
}

__device__ __forceinline__ void conv_row(float4& acc, const Row& r,
                                         const float4& k0, const float4& k1, const float4& k2) {
    acc.x += k0.x * r.lm  + k1.x * r.v.x + k2.x * r.v.y;
    acc.y += k0.y * r.v.x + k1.y * r.v.y + k2.y * r.v.z;
    acc.z += k0.z * r.v.y + k1.z * r.v.z + k2.z * r.v.w;
    acc.w += k0.w * r.v.z + k1.w * r.v.w + k2.w * r.rp;
}

__global__ __launch_bounds__(256) void ddf_kernel(const float* __restrict__ x,
                                                  const float* __restrict__ ker,
                                                  float* __restrict__ out) {
    const int b  = blockIdx.x;
    const int hs = b & 15;          // 16 h-segments
    const int cb = (b >> 4) & 7;    // 8 channel chunks of 32
    const int n  = b >> 7;          // batch
    const int h0 = hs * HSEG;

    const int t      = threadIdx.x;
    const int lane   = t & 63;
    const int wstrip = t & 15;
    const int w0     = wstrip << 2;
    const int chl    = t >> 4;      // 0..15

    // Stage this (n, h-segment)'s kernel taps into LDS: 9 taps x 4 rows x 64 w = 9 KB.
    __shared__ float4 klds[9 * 64];   // klds[tap*64 + dh*16 + wq]
    const float4* kerf4 = reinterpret_cast<const float4*>(ker) + (size_t)n * 9 * 1024;
    for (int j = t; j < 9 * 64; j += 256) {
        const int tap = j >> 6, q = j & 63;
        klds[j] = kerf4[(size_t)tap * 1024 + h0 * 16 + q];
    }

    const float* xc[NCH];
    float*       oc[NCH];
#pragma unroll
    for (int i = 0; i < NCH; ++i) {
        const int c = cb * CHUNK + i * 16 + chl;
        xc[i] = x   + ((size_t)(n * Cc + c) * Hh) * Ww;
        oc[i] = out + ((size_t)(n * Cc + c) * Hh) * Ww;
    }

    // Prime rolling window (rows h0-1, h0) while the LDS stage is in flight.
    Row r0[NCH], r1[NCH];
#pragma unroll
    for (int i = 0; i < NCH; ++i) {
        r0[i] = load_row(xc[i] + (size_t)(h0 - 1) * Ww, h0 > 0, w0, wstrip, lane);
        r1[i] = load_row(xc[i] + (size_t)h0 * Ww,       true,   w0, wstrip, lane);
    }
    __syncthreads();

#pragma unroll
    for (int dh = 0; dh < HSEG; ++dh) {
        const int h = h0 + dh;

        float4 kf[9];
#pragma unroll
        for (int tap = 0; tap < 9; ++tap)
            kf[tap] = klds[tap * 64 + dh * 16 + wstrip];   // 2-way bank alias: free

        const bool vnext = (h + 1) < Hh;   // block-uniform
        Row r2[NCH];
#pragma unroll
        for (int i = 0; i < NCH; ++i)
            r2[i] = load_row(xc[i] + (size_t)(h + 1) * Ww, vnext, w0, wstrip, lane);

#pragma unroll
        for (int i = 0; i < NCH; ++i) {
            float4 acc = make_float4(0.f, 0.f, 0.f, 0.f);
            conv_row(acc, r0[i], kf[0], kf[1], kf[2]);
            conv_row(acc, r1[i], kf[3], kf[4], kf[5]);
            conv_row(acc, r2[i], kf[6], kf[7], kf[8]);
            *reinterpret_cast<float4*>(oc[i] + (size_t)h * Ww + w0) = acc;
            r0[i] = r1[i];
            r1[i] = r2[i];
        }
    }
}

extern "C" void kernel_launch(void* const* d_in, const int* in_sizes, int n_in,
                              void* d_out, int out_size, void* d_ws, size_t ws_size,
                              hipStream_t stream) {
    const float* x   = (const float*)d_in[0];
    const float* ker = (const float*)d_in[1];
    float* out = (float*)d_out;

    const int grid = 8 * (Cc / CHUNK) * (Hh / HSEG);  // 8 * 8 * 16 = 1024
    ddf_kernel<<<grid, 256, 0, stream>>>(x, ker, out);
}